// Round 9
// baseline (172.998 us; speedup 1.0000x reference)
//
#include <hip/hip_runtime.h>
#include <hip/hip_bf16.h>

// Problem constants (fixed by reference)
#define NROWS 8192
#define HDIM  2048
#define EXP   8
#define RANK  8

typedef float  f32x4  __attribute__((ext_vector_type(4)));
typedef __bf16 bf16x8 __attribute__((ext_vector_type(8)));

// async global->LDS, 16B per lane; LDS dest must be wave-uniform (HW: base + lane*16)
__device__ __forceinline__ void gload_lds16(const void* g, void* l) {
  __builtin_amdgcn_global_load_lds((const __attribute__((address_space(1))) void*)g,
                                   (__attribute__((address_space(3))) void*)l, 16, 0, 0);
}

// ---------- K1: merged prep (x cast | W1 transpose-cast | A transpose-cast) ----------
__global__ __launch_bounds__(256) void k_prep(const float* __restrict__ x,
                                              const float* __restrict__ W1,
                                              const float* __restrict__ A,
                                              __hip_bfloat16* __restrict__ xb,
                                              __hip_bfloat16* __restrict__ w1t,
                                              __hip_bfloat16* __restrict__ at) {
  __shared__ float s[64][65];
  const int bid = blockIdx.x;
  if (bid < 8192) {
    // x f32 -> bf16, 8 elems/thread
    size_t i = ((size_t)bid * 256 + threadIdx.x) * 8;
    float4 a = *(const float4*)(x + i);
    float4 b = *(const float4*)(x + i + 4);
    union { __hip_bfloat16 h[8]; int4 v; } u;
    u.h[0] = __float2bfloat16(a.x); u.h[1] = __float2bfloat16(a.y);
    u.h[2] = __float2bfloat16(a.z); u.h[3] = __float2bfloat16(a.w);
    u.h[4] = __float2bfloat16(b.x); u.h[5] = __float2bfloat16(b.y);
    u.h[6] = __float2bfloat16(b.z); u.h[7] = __float2bfloat16(b.w);
    *(int4*)(xb + i) = u.v;
  } else if (bid < 9216) {
    // W1 [k][n] -> W1T [n][k] bf16, 64x64 LDS tile
    int b = bid - 8192;
    int n0 = (b & 31) * 64, k0 = (b >> 5) * 64;
    for (int i = 0; i < 16; ++i) {
      int idx = threadIdx.x + i * 256;
      int r = idx >> 6, c = idx & 63;
      s[r][c] = W1[(size_t)(k0 + r) * HDIM + n0 + c];
    }
    __syncthreads();
    for (int i = 0; i < 16; ++i) {
      int idx = threadIdx.x + i * 256;
      int r = idx >> 6, c = idx & 63;
      w1t[(size_t)(n0 + r) * HDIM + k0 + c] = __float2bfloat16(s[c][r]);
    }
  } else {
    // A [E][H][R] -> AT [E*R][H] bf16
    int b = bid - 9216;
    int e = b >> 3, ht = b & 7;
    float* sf = &s[0][0];
    const float* src = A + (size_t)e * (HDIM * RANK) + (size_t)ht * 256 * RANK;
    for (int i = 0; i < 8; ++i) sf[threadIdx.x + i * 256] = src[threadIdx.x + i * 256];
    __syncthreads();
    for (int i = 0; i < 8; ++i) {
      int idx = threadIdx.x + i * 256;
      int r = idx >> 8, hh = idx & 255;
      at[(size_t)(e * RANK + r) * HDIM + ht * 256 + hh] = __float2bfloat16(sf[hh * 8 + r]);
    }
  }
}

// ---------- K3: h = relu(x @ W1 + b1) + router logit partials + t = x @ A ----------
// 256x256 MFMA, 8 waves (2Mx4N), BK=64, 144KB LDS, 3-bit row-XOR swizzle
// (SQ_LDS_BANK_CONFLICT=0 verified R4), bijective XCD swizzle, setprio.
// R8 restructure: TWO barriers per K-tile (was 8) + no sched_barrier pinning.
//   HEAD {vmcnt(2); s_barrier}: per-tile issue order is Alo' 2, Ahi' 2, Blo'' 2,
//     T' 1, Bhi'' 2 (9/tile). At head of tile t the newest load t needs is T(t)
//     (3rd-newest; only Bhi(t+1)x2 younger) -> vmcnt(2). Barrier then makes all
//     waves' tile-t stages visible AND closes every tile-(t-1) LDS read, so the
//     A[bn]/T[bn] stages issued after it are WAR-safe.
//   MID {s_barrier}: after all B(t) ds_reads, before B(t+2)/T(t+1) stages
//     (WAR on B[b]). gload-land latency (~500cy) >> pending ds_read (~120cy)
//     covers issued-not-complete reads (m201's accepted pattern).
// Two 32-MFMA batches/tile -> waves drift freely inside batches; compiler
// inserts fine-grained lgkmcnt (m97 evidence), no order pinning (m141 evidence).
__global__ __launch_bounds__(512, 2) void k_gemm_h8(const __hip_bfloat16* __restrict__ X,
                                                    const __hip_bfloat16* __restrict__ WT,
                                                    const float* __restrict__ b1,
                                                    const float* __restrict__ W2,
                                                    const __hip_bfloat16* __restrict__ AT,
                                                    float* __restrict__ plog,
                                                    float* __restrict__ tmat) {
  extern __shared__ char lds[];
  char* ldsA = lds;                 // [2 buf][2 half][128 rows][64 k] bf16 = 64KB
  char* ldsB = lds + 65536;         // same
  char* ldsT = lds + 131072;        // [2 buf][64 rows][64 k] bf16 = 16KB
  const int tid = threadIdx.x;
  const int wid = tid >> 6, lane = tid & 63;
  const int wr = wid >> 2, wc = wid & 3;        // 2 x 4 wave grid
  const int g = lane >> 4, c16 = lane & 15;
  const int xm = (c16 & 7) << 4;                // read-side swizzle XOR (3 row bits -> chunk)
  const int lin = blockIdx.y * 8 + blockIdx.x;  // gridDim.x == 8
  const int nid = (lin & 7) * 32 + (lin >> 3);  // bijective XCD remap (256 % 8 == 0)
  const int cb = nid & 7, rb = nid >> 3;
  const int m0 = rb * 256, n0 = cb * 256;
  const int NT = HDIM / 64;                     // 32 K-tiles

  // stage-source geometry (inverse swizzle: logical chunk = phys chunk ^ (row&7))
  int srow[2], scol[2];
#pragma unroll
  for (int q = 0; q < 2; ++q) {
    int L = (q * 512 + tid) * 16;               // linear phys byte within 16KB half
    int row = L >> 7;
    int chunkp = (L >> 4) & 7;
    srow[q] = row;
    scol[q] = (chunkp ^ (row & 7)) << 3;        // bf16 elements (chunk*8)
  }
  auto stage = [&](const __hip_bfloat16* gb, int rowBase, int kBase, char* half) {
    gload_lds16(gb + (size_t)(rowBase + srow[0]) * HDIM + kBase + scol[0], half + tid * 16);
    gload_lds16(gb + (size_t)(rowBase + srow[1]) * HDIM + kBase + scol[1], half + 8192 + tid * 16);
  };
  // T stage: 8KB = 512 threads x 16B (one gload each); same row-XOR pre-swizzle
  auto stageT = [&](int kBase, char* dstT) {
    int row = tid >> 3;
    int col = (((tid & 7) ^ (row & 7)) << 3);
    gload_lds16(AT + (size_t)row * HDIM + kBase + col, dstT + tid * 16);
  };
  auto ldA = [&](int b, int fr, int ks) -> bf16x8 {
    int byte = (((fr << 4) + c16) << 7) + (ks << 6) + (g << 4);
    return *(const bf16x8*)(ldsA + b * 32768 + wr * 16384 + (byte ^ xm));
  };
  auto ldB = [&](int b, int fc, int ks) -> bf16x8 {
    int byte = (((((wc & 1) << 6) + (fc << 4) + c16)) << 7) + (ks << 6) + (g << 4);
    return *(const bf16x8*)(ldsB + b * 32768 + (wc >> 1) * 16384 + (byte ^ xm));
  };
  // t-GEMM A-operand: X row arow = cb*32 + wr*16 + c16 (row&7 == c16&7 -> same xm)
  auto ldAt = [&](int b, int ks) -> bf16x8 {
    int arow = cb * 32 + wr * 16 + c16;
    int byte = ((arow & 127) << 7) + (ks << 6) + (g << 4);
    return *(const bf16x8*)(ldsA + b * 32768 + (arow >> 7) * 16384 + (byte ^ xm));
  };
  // t-GEMM B-operand: AT row er = wc*16 + c16
  auto ldT = [&](int tb, int ks) -> bf16x8 {
    int byte = (((wc << 4) + c16) << 7) + (ks << 6) + (g << 4);
    return *(const bf16x8*)(ldsT + tb * 8192 + (byte ^ xm));
  };

  f32x4 acc[8][4] = {};
  f32x4 acc_t = {};

  // ---- prologue: A(0) 4, B(0) 4, T(0) 1, B(1) 4 = 13 issues; the t=0 head
  // vmcnt(2)+barrier provides the visibility wait ----
  stage(X,  m0,       0,  ldsA);
  stage(X,  m0 + 128, 0,  ldsA + 16384);
  stage(WT, n0,       0,  ldsB);
  stage(WT, n0 + 128, 0,  ldsB + 16384);
  stageT(0, ldsT);
  stage(WT, n0,       64, ldsB + 32768);
  stage(WT, n0 + 128, 64, ldsB + 32768 + 16384);

  for (int t = 0; t < NT; ++t) {
    const int b = t & 1;
    const int bn = b ^ 1;
    const int u1 = (t + 1 < NT) ? t + 1 : NT - 1; // clamped -> uniform issue counts
    const int u2 = (t + 2 < NT) ? t + 2 : NT - 1;
    bf16x8 af[4][2], b01[2][2], b23[2][2];

    // ---- HEAD: tile-t visibility + closes tile-(t-1) reads ----
    asm volatile("s_waitcnt vmcnt(2)" ::: "memory");
    __builtin_amdgcn_s_barrier();

    // A-stages for t+1 (A[bn]'s old readers all pre-head)
    stage(X, m0,       u1 * 64, ldsA + bn * 32768);
    stage(X, m0 + 128, u1 * 64, ldsA + bn * 32768 + 16384);

    // ---- batch 1: A fr0-3 x B fc0-3 (16 ds_read -> 32 MFMA) ----
#pragma unroll
    for (int fr = 0; fr < 4; ++fr)
#pragma unroll
      for (int ks = 0; ks < 2; ++ks) af[fr][ks] = ldA(b, fr, ks);
#pragma unroll
    for (int fc = 0; fc < 2; ++fc)
#pragma unroll
      for (int ks = 0; ks < 2; ++ks) { b01[fc][ks] = ldB(b, fc, ks); b23[fc][ks] = ldB(b, fc + 2, ks); }
    __builtin_amdgcn_s_setprio(1);
#pragma unroll
    for (int fr = 0; fr < 4; ++fr)
#pragma unroll
      for (int ks = 0; ks < 2; ++ks) {
#pragma unroll
        for (int fc = 0; fc < 2; ++fc) {
          acc[fr][fc]     = __builtin_amdgcn_mfma_f32_16x16x32_bf16(af[fr][ks], b01[fc][ks], acc[fr][fc], 0, 0, 0);
          acc[fr][fc + 2] = __builtin_amdgcn_mfma_f32_16x16x32_bf16(af[fr][ks], b23[fc][ks], acc[fr][fc + 2], 0, 0, 0);
        }
      }
    __builtin_amdgcn_s_setprio(0);

    // ---- batch-2 reads (A fr4-7 + t operands), then MID barrier, then stages ----
#pragma unroll
    for (int fr = 0; fr < 4; ++fr)
#pragma unroll
      for (int ks = 0; ks < 2; ++ks) af[fr][ks] = ldA(b, fr + 4, ks);
    bf16x8 ta0 = ldAt(b, 0), ta1 = ldAt(b, 1);
    bf16x8 tb0 = ldT(b, 0),  tb1 = ldT(b, 1);
    __builtin_amdgcn_s_barrier();                 // MID: B(t)/T(t) reads all issued
    stage(WT, n0,       u2 * 64, ldsB + b * 32768);
    stageT(u1 * 64, ldsT + bn * 8192);
    stage(WT, n0 + 128, u2 * 64, ldsB + b * 32768 + 16384);

    // ---- batch 2: A fr4-7 x B fc0-3 (32 MFMA) + 2 t-MFMA ----
    __builtin_amdgcn_s_setprio(1);
#pragma unroll
    for (int fr = 0; fr < 4; ++fr)
#pragma unroll
      for (int ks = 0; ks < 2; ++ks) {
#pragma unroll
        for (int fc = 0; fc < 2; ++fc) {
          acc[fr + 4][fc]     = __builtin_amdgcn_mfma_f32_16x16x32_bf16(af[fr][ks], b01[fc][ks], acc[fr + 4][fc], 0, 0, 0);
          acc[fr + 4][fc + 2] = __builtin_amdgcn_mfma_f32_16x16x32_bf16(af[fr][ks], b23[fc][ks], acc[fr + 4][fc + 2], 0, 0, 0);
        }
      }
    acc_t = __builtin_amdgcn_mfma_f32_16x16x32_bf16(ta0, tb0, acc_t, 0, 0, 0);
    acc_t = __builtin_amdgcn_mfma_f32_16x16x32_bf16(ta1, tb1, acc_t, 0, 0, 0);
    __builtin_amdgcn_s_setprio(0);
  }

  // ---- t write: block's disjoint 32-row slice; D: col=c16 (er), row=g*4+q ----
  {
    int trow = m0 + cb * 32 + wr * 16 + g * 4;
    int er = wc * 16 + c16;
#pragma unroll
    for (int q = 0; q < 4; ++q)
      tmat[(size_t)(trow + q) * 64 + er] = acc_t[q];
  }

  // ---- fused epilogue: router logit partials via LDS transpose-reduce ----
  asm volatile("s_waitcnt vmcnt(0)" ::: "memory");  // drain clamped-tail stages
  __builtin_amdgcn_s_barrier();
  float* red = (float*)lds;                      // 74KB < 144KB

  f32x4 w2lo[4], w2hi[4];
  float bias[4];
#pragma unroll
  for (int fc = 0; fc < 4; ++fc) {
    int col = n0 + wc * 64 + fc * 16 + c16;
    const float* wp = W2 + (size_t)col * EXP;
    w2lo[fc] = *(const f32x4*)wp;
    w2hi[fc] = *(const f32x4*)(wp + 4);
    bias[fc] = b1[col];
  }
  const int oidx = tid >> 1, prt = tid & 1;
  const int rrl = oidx >> 3, re = oidx & 7;      // reader's (rloc, e)
  for (int fr = 0; fr < 8; ++fr) {
#pragma unroll
    for (int r = 0; r < 4; ++r) {
      f32x4 p0 = {}, p1 = {};
#pragma unroll
      for (int fc = 0; fc < 4; ++fc) {
        float v = acc[fr][fc][r] + bias[fc];
        v = v > 0.f ? v : 0.f;                   // f32 h (no bf16 round-trip)
        p0 += v * w2lo[fc];
        p1 += v * w2hi[fc];
      }
      int base = (wc * 16 + c16) * 289 + (wr * 16 + g * 4 + r) * 9;
#pragma unroll
      for (int e = 0; e < 4; ++e) { red[base + e] = p0[e]; red[base + 4 + e] = p1[e]; }
    }
    __syncthreads();
    {
      float s = 0.f;
#pragma unroll
      for (int wq = 0; wq < 4; ++wq)
#pragma unroll
        for (int i = 0; i < 8; ++i)
          s += red[(wq * 16 + prt * 8 + i) * 289 + rrl * 9 + re];
      s += __shfl_xor(s, 1, 64);                 // combine prt halves
      if (prt == 0) {
        int grow = (rrl >> 4) * 128 + fr * 16 + (rrl & 15);
        plog[((size_t)cb * NROWS + m0 + grow) * 8 + re] = s;
      }
    }
    __syncthreads();
  }
}

// ---------- K6: fused softmax + out[n][h] = sum_er (t*w) * B[er][h] ----------
// thread t owns (row = t>>3, expert e = t&7): computes softmax weight inline
// (8-lane shfl group reduce), scales its own t-chunk er0 = e*8..e*8+8.
__global__ __launch_bounds__(256) void k_final(const float* __restrict__ plog,
                                               const float* __restrict__ b2,
                                               const float* __restrict__ tmat,
                                               const float* __restrict__ Bm,
                                               float* __restrict__ out) {
  __shared__ float cs[32][64];
  const int t = threadIdx.x;
  const int n0 = (blockIdx.x >> 3) * 32;
  const int col0 = (blockIdx.x & 7) * 256;
  {
    int row = t >> 3, e = t & 7;
    float lg = b2[e];
#pragma unroll
    for (int cbk = 0; cbk < 8; ++cbk)
      lg += plog[((size_t)cbk * NROWS + n0 + row) * 8 + e];
    float m = lg;
#pragma unroll
    for (int off = 4; off; off >>= 1) m = fmaxf(m, __shfl_xor(m, off, 64));
    float ex = __expf(lg - m);
    float s = ex;
#pragma unroll
    for (int off = 4; off; off >>= 1) s += __shfl_xor(s, off, 64);
    float w = ex / s;
    const float* src = tmat + (size_t)(n0 + row) * 64 + e * 8;
    *(f32x4*)&cs[row][e * 8]     = *(const f32x4*)src * w;
    *(f32x4*)&cs[row][e * 8 + 4] = *(const f32x4*)(src + 4) * w;
  }
  __syncthreads();
  const int rg = t >> 5;
  const int cg = t & 31;
  const int cc = col0 + cg * 8;
  f32x4 acc0[4] = {}, acc1[4] = {};
#pragma unroll 4
  for (int er = 0; er < 64; ++er) {
    f32x4 b0  = *(const f32x4*)&Bm[(size_t)er * HDIM + cc];
    f32x4 b1v = *(const f32x4*)&Bm[(size_t)er * HDIM + cc + 4];
#pragma unroll
    for (int r = 0; r < 4; ++r) {
      float cv = cs[rg * 4 + r][er];
      acc0[r] += cv * b0;
      acc1[r] += cv * b1v;
    }
  }
#pragma unroll
  for (int r = 0; r < 4; ++r) {
    size_t o = (size_t)(n0 + rg * 4 + r) * HDIM + cc;
    *(f32x4*)&out[o] = acc0[r];
    *(f32x4*)&out[o + 4] = acc1[r];
  }
}

extern "C" void kernel_launch(void* const* d_in, const int* in_sizes, int n_in,
                              void* d_out, int out_size, void* d_ws, size_t ws_size,
                              hipStream_t stream) {
  const float* x  = (const float*)d_in[0];
  const float* W1 = (const float*)d_in[1];
  const float* b1 = (const float*)d_in[2];
  const float* W2 = (const float*)d_in[3];
  const float* b2 = (const float*)d_in[4];
  const float* A  = (const float*)d_in[5];
  const float* B  = (const float*)d_in[6];
  float* out = (float*)d_out;

  char* ws = (char*)d_ws;
  // ws layout (bytes):
  //   xb   [8192*2048] bf16 : 33,554,432
  //   w1t  [2048*2048] bf16 :  8,388,608
  //   plog [8*8192*8]  f32  :  2,097,152
  //   at   [64*2048]   bf16 :    262,144
  //   (unused)              :    262,144
  //   tmat [8192*64]   f32  :  2,097,152
  __hip_bfloat16* xb  = (__hip_bfloat16*)(ws);
  __hip_bfloat16* w1t = (__hip_bfloat16*)(ws + 33554432);
  float* plog         = (float*)(ws + 41943040);
  __hip_bfloat16* at  = (__hip_bfloat16*)(ws + 75497472);
  float* tmat         = (float*)(ws + 76021760);
  if (ws_size < 84410368) return;  // insufficient scratch -> fail loudly

  hipFuncSetAttribute((const void*)k_gemm_h8,
                      hipFuncAttributeMaxDynamicSharedMemorySize, 147456);

  k_prep<<<8192 + 1024 + 64, 256, 0, stream>>>(x, W1, A, xb, w1t, at);
  k_gemm_h8<<<dim3(HDIM / 256, NROWS / 256), 512, 147456, stream>>>(xb, w1t, b1, W2, at, plog, tmat);
  k_final<<<2048, 256, 0, stream>>>(plog, b2, tmat, B, out);
}

// Round 10
// 112.514 us; speedup vs baseline: 1.5376x; 1.5376x over previous
//
#include <hip/hip_runtime.h>
#include <hip/hip_bf16.h>

// Problem constants (fixed by reference)
#define NROWS 8192
#define HDIM  2048
#define EXP   8
#define RANK  8

typedef float  f32x4  __attribute__((ext_vector_type(4)));
typedef __bf16 bf16x8 __attribute__((ext_vector_type(8)));

// async global->LDS, 16B per lane; LDS dest must be wave-uniform (HW: base + lane*16)
__device__ __forceinline__ void gload_lds16(const void* g, void* l) {
  __builtin_amdgcn_global_load_lds((const __attribute__((address_space(1))) void*)g,
                                   (__attribute__((address_space(3))) void*)l, 16, 0, 0);
}

#define FENCE asm volatile("" ::: "memory")
// R8 LESSON (frozen): collapsing the 4-phase/8-barrier rhythm to 2 barriers + two
// 32-MFMA batches regressed 76->111us (MfmaUtil 38->25.5) — the per-phase barriers
// create the wave role-diversity that overlaps LDS-pipe staging with MFMA (m196).
// Keep THIS structure.
#define SYNC_P1 do { FENCE; asm volatile("s_waitcnt vmcnt(4)" ::: "memory"); \
  __builtin_amdgcn_s_barrier(); __builtin_amdgcn_sched_barrier(0); FENCE; } while (0)
#define SYNC_MIDB do { FENCE; __builtin_amdgcn_s_barrier(); \
  __builtin_amdgcn_sched_barrier(0); FENCE; } while (0)
#define SYNC_END do { FENCE; __builtin_amdgcn_sched_barrier(0); \
  __builtin_amdgcn_s_barrier(); __builtin_amdgcn_sched_barrier(0); FENCE; } while (0)

// ---------- K1: merged prep (x cast | W1 transpose | A transpose | B transpose) ----------
__global__ __launch_bounds__(256) void k_prep(const float* __restrict__ x,
                                              const float* __restrict__ W1,
                                              const float* __restrict__ A,
                                              const float* __restrict__ B,
                                              __hip_bfloat16* __restrict__ xb,
                                              __hip_bfloat16* __restrict__ w1t,
                                              __hip_bfloat16* __restrict__ at,
                                              __hip_bfloat16* __restrict__ bt) {
  __shared__ float s[64][65];
  const int bid = blockIdx.x;
  if (bid < 8192) {
    // x f32 -> bf16, 8 elems/thread
    size_t i = ((size_t)bid * 256 + threadIdx.x) * 8;
    float4 a = *(const float4*)(x + i);
    float4 b = *(const float4*)(x + i + 4);
    union { __hip_bfloat16 h[8]; int4 v; } u;
    u.h[0] = __float2bfloat16(a.x); u.h[1] = __float2bfloat16(a.y);
    u.h[2] = __float2bfloat16(a.z); u.h[3] = __float2bfloat16(a.w);
    u.h[4] = __float2bfloat16(b.x); u.h[5] = __float2bfloat16(b.y);
    u.h[6] = __float2bfloat16(b.z); u.h[7] = __float2bfloat16(b.w);
    *(int4*)(xb + i) = u.v;
  } else if (bid < 9216) {
    // W1 [k][n] -> W1T [n][k] bf16, 64x64 LDS tile
    int b = bid - 8192;
    int n0 = (b & 31) * 64, k0 = (b >> 5) * 64;
    for (int i = 0; i < 16; ++i) {
      int idx = threadIdx.x + i * 256;
      int r = idx >> 6, c = idx & 63;
      s[r][c] = W1[(size_t)(k0 + r) * HDIM + n0 + c];
    }
    __syncthreads();
    for (int i = 0; i < 16; ++i) {
      int idx = threadIdx.x + i * 256;
      int r = idx >> 6, c = idx & 63;
      w1t[(size_t)(n0 + r) * HDIM + k0 + c] = __float2bfloat16(s[c][r]);
    }
  } else if (bid < 9280) {
    // A [E][H][R] -> AT [E*R][H] bf16
    int b = bid - 9216;
    int e = b >> 3, ht = b & 7;
    float* sf = &s[0][0];
    const float* src = A + (size_t)e * (HDIM * RANK) + (size_t)ht * 256 * RANK;
    for (int i = 0; i < 8; ++i) sf[threadIdx.x + i * 256] = src[threadIdx.x + i * 256];
    __syncthreads();
    for (int i = 0; i < 8; ++i) {
      int idx = threadIdx.x + i * 256;
      int r = idx >> 8, hh = idx & 255;
      at[(size_t)(e * RANK + r) * HDIM + ht * 256 + hh] = __float2bfloat16(sf[hh * 8 + r]);
    }
  } else {
    // B [er 64][h 2048] -> Bt [h][er] bf16, 64x64 tile (32 blocks)
    int b = bid - 9280;
    int n0 = b * 64;                       // h base
    for (int i = 0; i < 16; ++i) {
      int idx = threadIdx.x + i * 256;
      int r = idx >> 6, c = idx & 63;      // r = er, c = h offset
      s[r][c] = B[(size_t)r * HDIM + n0 + c];
    }
    __syncthreads();
    for (int i = 0; i < 16; ++i) {
      int idx = threadIdx.x + i * 256;
      int r = idx >> 6, c = idx & 63;      // r = h offset, c = er
      bt[(size_t)(n0 + r) * 64 + c] = __float2bfloat16(s[c][r]);
    }
  }
}

// ---------- K3: h = relu(x @ W1 + b1) + router logit partials + t = x @ A ----------
// EXACT R7 structure (proven 76us / 38% MfmaUtil): 256x256, 8 waves (2Mx4N), BK=64,
// 144KB LDS, 3-bit row-XOR swizzle (bank-conflict-free), bijective XCD swizzle,
// 4 phases x {reads | stage | barrier | setprio MFMA | barrier}, one vmcnt(4)/tile at P1.
__global__ __launch_bounds__(512, 2) void k_gemm_h8(const __hip_bfloat16* __restrict__ X,
                                                    const __hip_bfloat16* __restrict__ WT,
                                                    const float* __restrict__ b1,
                                                    const float* __restrict__ W2,
                                                    const __hip_bfloat16* __restrict__ AT,
                                                    float* __restrict__ plog,
                                                    float* __restrict__ tmat) {
  extern __shared__ char lds[];
  char* ldsA = lds;                 // [2 buf][2 half][128 rows][64 k] bf16 = 64KB
  char* ldsB = lds + 65536;         // same
  char* ldsT = lds + 131072;        // [2 buf][64 rows][64 k] bf16 = 16KB
  const int tid = threadIdx.x;
  const int wid = tid >> 6, lane = tid & 63;
  const int wr = wid >> 2, wc = wid & 3;        // 2 x 4 wave grid
  const int g = lane >> 4, c16 = lane & 15;
  const int xm = (c16 & 7) << 4;                // read-side swizzle XOR (3 row bits -> chunk)
  const int lin = blockIdx.y * 8 + blockIdx.x;  // gridDim.x == 8
  const int nid = (lin & 7) * 32 + (lin >> 3);  // bijective XCD remap (256 % 8 == 0)
  const int cb = nid & 7, rb = nid >> 3;
  const int m0 = rb * 256, n0 = cb * 256;
  const int NT = HDIM / 64;                     // 32 K-tiles

  int srow[2], scol[2];
#pragma unroll
  for (int q = 0; q < 2; ++q) {
    int L = (q * 512 + tid) * 16;               // linear phys byte within 16KB half
    int row = L >> 7;
    int chunkp = (L >> 4) & 7;
    srow[q] = row;
    scol[q] = (chunkp ^ (row & 7)) << 3;        // bf16 elements (chunk*8)
  }
  auto stage = [&](const __hip_bfloat16* gb, int rowBase, int kBase, char* half) {
    gload_lds16(gb + (size_t)(rowBase + srow[0]) * HDIM + kBase + scol[0], half + tid * 16);
    gload_lds16(gb + (size_t)(rowBase + srow[1]) * HDIM + kBase + scol[1], half + 8192 + tid * 16);
  };
  auto stageT = [&](int kBase, char* dstT) {
    int row = tid >> 3;
    int col = (((tid & 7) ^ (row & 7)) << 3);
    gload_lds16(AT + (size_t)row * HDIM + kBase + col, dstT + tid * 16);
  };
  auto ldA = [&](int b, int fr, int ks) -> bf16x8 {
    int byte = (((fr << 4) + c16) << 7) + (ks << 6) + (g << 4);
    return *(const bf16x8*)(ldsA + b * 32768 + wr * 16384 + (byte ^ xm));
  };
  auto ldB = [&](int b, int fc, int ks) -> bf16x8 {
    int byte = (((((wc & 1) << 6) + (fc << 4) + c16)) << 7) + (ks << 6) + (g << 4);
    return *(const bf16x8*)(ldsB + b * 32768 + (wc >> 1) * 16384 + (byte ^ xm));
  };
  auto ldAt = [&](int b, int ks) -> bf16x8 {
    int arow = cb * 32 + wr * 16 + c16;
    int byte = ((arow & 127) << 7) + (ks << 6) + (g << 4);
    return *(const bf16x8*)(ldsA + b * 32768 + (arow >> 7) * 16384 + (byte ^ xm));
  };
  auto ldT = [&](int tb, int ks) -> bf16x8 {
    int byte = (((wc << 4) + c16) << 7) + (ks << 6) + (g << 4);
    return *(const bf16x8*)(ldsT + tb * 8192 + (byte ^ xm));
  };

  f32x4 acc[8][4] = {};
  f32x4 acc_t = {};

  // ---- prologue: A(0) 4, B(0) 4, T(0) 1, B(1) 4 = 13 issues; vmcnt(5) covers A0/B0 ----
  stage(X,  m0,       0,  ldsA);
  stage(X,  m0 + 128, 0,  ldsA + 16384);
  stage(WT, n0,       0,  ldsB);
  stage(WT, n0 + 128, 0,  ldsB + 16384);
  stageT(0, ldsT);
  stage(WT, n0,       64, ldsB + 32768);
  stage(WT, n0 + 128, 64, ldsB + 32768 + 16384);
  FENCE; asm volatile("s_waitcnt vmcnt(5)" ::: "memory");
  __builtin_amdgcn_s_barrier();
  __builtin_amdgcn_sched_barrier(0); FENCE;

  for (int t = 0; t < NT; ++t) {
    const int b = t & 1;
    const int bn = b ^ 1;
    const int u1 = (t + 1 < NT) ? t + 1 : NT - 1; // clamped -> uniform vmcnt counts
    const int u2 = (t + 2 < NT) ? t + 2 : NT - 1;
    bf16x8 af[4][2], b01[2][2], b23[2][2];

    // ---------- P1: read A fr0-3 + B fc0-1 | stage A-lo(t+1) | vmcnt(4) | MFMA ----------
#pragma unroll
    for (int fr = 0; fr < 4; ++fr)
#pragma unroll
      for (int ks = 0; ks < 2; ++ks) af[fr][ks] = ldA(b, fr, ks);
#pragma unroll
    for (int fc = 0; fc < 2; ++fc)
#pragma unroll
      for (int ks = 0; ks < 2; ++ks) b01[fc][ks] = ldB(b, fc, ks);
    stage(X, m0, u1 * 64, ldsA + bn * 32768);
    SYNC_P1;
    __builtin_amdgcn_s_setprio(1);
#pragma unroll
    for (int fr = 0; fr < 4; ++fr)
#pragma unroll
      for (int fc = 0; fc < 2; ++fc)
#pragma unroll
        for (int ks = 0; ks < 2; ++ks)
          acc[fr][fc] = __builtin_amdgcn_mfma_f32_16x16x32_bf16(af[fr][ks], b01[fc][ks], acc[fr][fc], 0, 0, 0);
    __builtin_amdgcn_s_setprio(0);
    SYNC_END;

    // ---------- P2: read B fc2-3 | stage A-hi(t+1) | MFMA ----------
#pragma unroll
    for (int fc = 0; fc < 2; ++fc)
#pragma unroll
      for (int ks = 0; ks < 2; ++ks) b23[fc][ks] = ldB(b, fc + 2, ks);
    stage(X, m0 + 128, u1 * 64, ldsA + bn * 32768 + 16384);
    SYNC_MIDB;
    __builtin_amdgcn_s_setprio(1);
#pragma unroll
    for (int fr = 0; fr < 4; ++fr)
#pragma unroll
      for (int fc = 0; fc < 2; ++fc)
#pragma unroll
        for (int ks = 0; ks < 2; ++ks)
          acc[fr][fc + 2] = __builtin_amdgcn_mfma_f32_16x16x32_bf16(af[fr][ks], b23[fc][ks], acc[fr][fc + 2], 0, 0, 0);
    __builtin_amdgcn_s_setprio(0);
    SYNC_END;

    // ---------- P3: read A fr4-7 | stage B-lo(t+2), T(t+1) | MFMA ----------
#pragma unroll
    for (int fr = 0; fr < 4; ++fr)
#pragma unroll
      for (int ks = 0; ks < 2; ++ks) af[fr][ks] = ldA(b, fr + 4, ks);
    stage(WT, n0, u2 * 64, ldsB + b * 32768);
    stageT(u1 * 64, ldsT + bn * 8192);
    SYNC_MIDB;
    __builtin_amdgcn_s_setprio(1);
#pragma unroll
    for (int fr = 0; fr < 4; ++fr)
#pragma unroll
      for (int fc = 0; fc < 2; ++fc)
#pragma unroll
        for (int ks = 0; ks < 2; ++ks)
          acc[fr + 4][fc + 2] = __builtin_amdgcn_mfma_f32_16x16x32_bf16(af[fr][ks], b23[fc][ks], acc[fr + 4][fc + 2], 0, 0, 0);
    __builtin_amdgcn_s_setprio(0);
    SYNC_END;

    // ---------- P4: read t-frags | stage B-hi(t+2) | MFMA + 2 t-MFMA ----------
    bf16x8 ta0 = ldAt(b, 0), ta1 = ldAt(b, 1);
    bf16x8 tb0 = ldT(b, 0),  tb1 = ldT(b, 1);
    stage(WT, n0 + 128, u2 * 64, ldsB + b * 32768 + 16384);
    SYNC_MIDB;
    __builtin_amdgcn_s_setprio(1);
#pragma unroll
    for (int fr = 0; fr < 4; ++fr)
#pragma unroll
      for (int fc = 0; fc < 2; ++fc)
#pragma unroll
        for (int ks = 0; ks < 2; ++ks)
          acc[fr + 4][fc] = __builtin_amdgcn_mfma_f32_16x16x32_bf16(af[fr][ks], b01[fc][ks], acc[fr + 4][fc], 0, 0, 0);
    acc_t = __builtin_amdgcn_mfma_f32_16x16x32_bf16(ta0, tb0, acc_t, 0, 0, 0);
    acc_t = __builtin_amdgcn_mfma_f32_16x16x32_bf16(ta1, tb1, acc_t, 0, 0, 0);
    __builtin_amdgcn_s_setprio(0);
    SYNC_END;
  }

  // ---- t write: block's disjoint 32-row slice; D: col=c16 (er), row=g*4+q ----
  {
    int trow = m0 + cb * 32 + wr * 16 + g * 4;
    int er = wc * 16 + c16;
#pragma unroll
    for (int q = 0; q < 4; ++q)
      tmat[(size_t)(trow + q) * 64 + er] = acc_t[q];
  }

  // ---- fused epilogue: router logit partials via LDS transpose-reduce ----
  FENCE; asm volatile("s_waitcnt vmcnt(0)" ::: "memory");
  __builtin_amdgcn_s_barrier(); FENCE;
  float* red = (float*)lds;                      // 74KB < 144KB

  f32x4 w2lo[4], w2hi[4];
  float bias[4];
#pragma unroll
  for (int fc = 0; fc < 4; ++fc) {
    int col = n0 + wc * 64 + fc * 16 + c16;
    const float* wp = W2 + (size_t)col * EXP;
    w2lo[fc] = *(const f32x4*)wp;
    w2hi[fc] = *(const f32x4*)(wp + 4);
    bias[fc] = b1[col];
  }
  const int oidx = tid >> 1, prt = tid & 1;
  const int rrl = oidx >> 3, re = oidx & 7;      // reader's (rloc, e)
  for (int fr = 0; fr < 8; ++fr) {
#pragma unroll
    for (int r = 0; r < 4; ++r) {
      f32x4 p0 = {}, p1 = {};
#pragma unroll
      for (int fc = 0; fc < 4; ++fc) {
        float v = acc[fr][fc][r] + bias[fc];
        v = v > 0.f ? v : 0.f;                   // f32 h (no bf16 round-trip)
        p0 += v * w2lo[fc];
        p1 += v * w2hi[fc];
      }
      int base = (wc * 16 + c16) * 289 + (wr * 16 + g * 4 + r) * 9;
#pragma unroll
      for (int e = 0; e < 4; ++e) { red[base + e] = p0[e]; red[base + 4 + e] = p1[e]; }
    }
    __syncthreads();
    {
      float s = 0.f;
#pragma unroll
      for (int wq = 0; wq < 4; ++wq)
#pragma unroll
        for (int i = 0; i < 8; ++i)
          s += red[(wq * 16 + prt * 8 + i) * 289 + rrl * 9 + re];
      s += __shfl_xor(s, 1, 64);                 // combine prt halves
      if (prt == 0) {
        int grow = (rrl >> 4) * 128 + fr * 16 + (rrl & 15);
        plog[((size_t)cb * NROWS + m0 + grow) * 8 + re] = s;
      }
    }
    __syncthreads();
  }
}

// ---------- K6: fused softmax + MFMA out = (w .* t) @ B ----------
// 1024 blocks (256 row-groups x 4 col-slices), 256 thr (4 waves), 68KB dyn LDS.
// c[32x64] built in bf16 (softmax inline), Bt slice [512][64] bf16 staged via
// gload_lds with the verified row-XOR swizzle; MFMA 16x16x32 (patterns verbatim
// from k_gemm_h8's verified ldA/ldB/D-layout). Write-bound (~64MB out).
__global__ __launch_bounds__(256) void k_final(const float* __restrict__ plog,
                                               const float* __restrict__ b2,
                                               const float* __restrict__ tmat,
                                               const __hip_bfloat16* __restrict__ Bt,
                                               float* __restrict__ out) {
  extern __shared__ char flds[];
  char* cl = flds;            // [32 rows][64 er] bf16, swizzled, 4KB
  char* bl = flds + 4096;     // [512 hcols][64 er] bf16, swizzled, 64KB
  const int t = threadIdx.x;
  const int wv = t >> 6, lane = t & 63;
  const int g = lane >> 4, c16 = lane & 15;
  const int xm = (c16 & 7) << 4;
  const int r0 = (blockIdx.x >> 2) * 32;
  const int c0 = (blockIdx.x & 3) * 512;

  // stage Bt slice: 16 rounds x 256 thr x 16B (linear dest, inverse-swizzled src)
  for (int i = 0; i < 16; ++i) {
    int L = (i * 256 + t) * 16;
    int row = L >> 7;
    int chunkp = (L >> 4) & 7;
    int scol = (chunkp ^ (row & 7)) << 3;
    gload_lds16(Bt + (size_t)(c0 + row) * 64 + scol, bl + L);
  }
  // softmax + weighted c (bf16) into cl
  {
    int row = t >> 3, e = t & 7;
    float lg = b2[e];
#pragma unroll
    for (int cbk = 0; cbk < 8; ++cbk)
      lg += plog[((size_t)cbk * NROWS + r0 + row) * 8 + e];
    float m = lg;
#pragma unroll
    for (int off = 4; off; off >>= 1) m = fmaxf(m, __shfl_xor(m, off, 64));
    float ex = __expf(lg - m);
    float s = ex;
#pragma unroll
    for (int off = 4; off; off >>= 1) s += __shfl_xor(s, off, 64);
    float w = ex / s;
    const float* src = tmat + (size_t)(r0 + row) * 64 + e * 8;
    f32x4 v0 = *(const f32x4*)src * w;
    f32x4 v1 = *(const f32x4*)(src + 4) * w;
    union { __hip_bfloat16 h[8]; int4 q; } u;
#pragma unroll
    for (int j = 0; j < 4; ++j) { u.h[j] = __float2bfloat16(v0[j]); u.h[4 + j] = __float2bfloat16(v1[j]); }
    int byte = (row << 7) + (e << 4);
    *(int4*)(cl + (byte ^ ((row & 7) << 4))) = u.q;
  }
  asm volatile("s_waitcnt vmcnt(0)" ::: "memory");
  __syncthreads();

  auto ldc = [&](int mi, int ks) -> bf16x8 {
    int byte = (((mi << 4) + c16) << 7) + (ks << 6) + (g << 4);
    return *(const bf16x8*)(cl + (byte ^ xm));
  };
  auto ldb = [&](int nj, int ks) -> bf16x8 {
    int rowb = (wv << 7) + (nj << 4) + c16;
    int byte = (rowb << 7) + (ks << 6) + (g << 4);
    return *(const bf16x8*)(bl + (byte ^ xm));
  };
  bf16x8 cA[2][2];
#pragma unroll
  for (int mi = 0; mi < 2; ++mi)
#pragma unroll
    for (int ks = 0; ks < 2; ++ks) cA[mi][ks] = ldc(mi, ks);
  f32x4 acc[2][8] = {};
#pragma unroll
  for (int nj = 0; nj < 8; ++nj) {
    bf16x8 b0 = ldb(nj, 0), b1v = ldb(nj, 1);
#pragma unroll
    for (int mi = 0; mi < 2; ++mi) {
      acc[mi][nj] = __builtin_amdgcn_mfma_f32_16x16x32_bf16(cA[mi][0], b0,  acc[mi][nj], 0, 0, 0);
      acc[mi][nj] = __builtin_amdgcn_mfma_f32_16x16x32_bf16(cA[mi][1], b1v, acc[mi][nj], 0, 0, 0);
    }
  }
  // D: col=c16 (h within nj tile), row=4g+q (n rows)
#pragma unroll
  for (int mi = 0; mi < 2; ++mi)
#pragma unroll
    for (int nj = 0; nj < 8; ++nj)
#pragma unroll
      for (int q = 0; q < 4; ++q)
        out[(size_t)(r0 + mi * 16 + g * 4 + q) * HDIM + c0 + wv * 128 + nj * 16 + c16] = acc[mi][nj][q];
}

extern "C" void kernel_launch(void* const* d_in, const int* in_sizes, int n_in,
                              void* d_out, int out_size, void* d_ws, size_t ws_size,
                              hipStream_t stream) {
  const float* x  = (const float*)d_in[0];
  const float* W1 = (const float*)d_in[1];
  const float* b1 = (const float*)d_in[2];
  const float* W2 = (const float*)d_in[3];
  const float* b2 = (const float*)d_in[4];
  const float* A  = (const float*)d_in[5];
  const float* B  = (const float*)d_in[6];
  float* out = (float*)d_out;

  char* ws = (char*)d_ws;
  // ws layout (bytes):
  //   xb   [8192*2048] bf16 : 33,554,432
  //   w1t  [2048*2048] bf16 :  8,388,608
  //   plog [8*8192*8]  f32  :  2,097,152
  //   at   [64*2048]   bf16 :    262,144
  //   bt   [2048*64]   bf16 :    262,144
  //   tmat [8192*64]   f32  :  2,097,152
  __hip_bfloat16* xb  = (__hip_bfloat16*)(ws);
  __hip_bfloat16* w1t = (__hip_bfloat16*)(ws + 33554432);
  float* plog         = (float*)(ws + 41943040);
  __hip_bfloat16* at  = (__hip_bfloat16*)(ws + 75497472);
  __hip_bfloat16* bt  = (__hip_bfloat16*)(ws + 75759616);
  float* tmat         = (float*)(ws + 76021760);
  if (ws_size < 84410368) return;  // insufficient scratch -> fail loudly

  hipFuncSetAttribute((const void*)k_gemm_h8,
                      hipFuncAttributeMaxDynamicSharedMemorySize, 147456);
  hipFuncSetAttribute((const void*)k_final,
                      hipFuncAttributeMaxDynamicSharedMemorySize, 69632);

  k_prep<<<8192 + 1024 + 64 + 32, 256, 0, stream>>>(x, W1, A, B, xb, w1t, at, bt);
  k_gemm_h8<<<dim3(HDIM / 256, NROWS / 256), 512, 147456, stream>>>(xb, w1t, b1, W2, at, plog, tmat);
  k_final<<<1024, 256, 69632, stream>>>(plog, b2, tmat, bt, out);
}

// Round 11
// 111.728 us; speedup vs baseline: 1.5484x; 1.0070x over previous
//
#include <hip/hip_runtime.h>
#include <hip/hip_bf16.h>

// Problem constants (fixed by reference)
#define NROWS 8192
#define HDIM  2048
#define EXP   8
#define RANK  8

typedef float  f32x4  __attribute__((ext_vector_type(4)));
typedef __bf16 bf16x8 __attribute__((ext_vector_type(8)));

// async global->LDS, 16B per lane; LDS dest must be wave-uniform (HW: base + lane*16)
__device__ __forceinline__ void gload_lds16(const void* g, void* l) {
  __builtin_amdgcn_global_load_lds((const __attribute__((address_space(1))) void*)g,
                                   (__attribute__((address_space(3))) void*)l, 16, 0, 0);
}

#define FENCE asm volatile("" ::: "memory")
// R8 LESSON (frozen): keep the 4-phase/8-barrier rhythm + per-tile vmcnt(4) at P1.
// R10 change: sched_barrier(0) order-pins REMOVED (m141: pinning costs; m201's
// proven template has none here). FENCE memory-clobbers still stop any memory op
// (ds_read / gload_lds) from crossing a sync point; compiler-emitted ds_reads get
// native lgkmcnt tracking so MFMA can't run ahead of its operands (rule #18 applies
// only to inline-asm ds_reads, which we don't use).
#define SYNC_P1 do { FENCE; asm volatile("s_waitcnt vmcnt(4)" ::: "memory"); \
  __builtin_amdgcn_s_barrier(); FENCE; } while (0)
#define SYNC_MIDB do { FENCE; __builtin_amdgcn_s_barrier(); FENCE; } while (0)
#define SYNC_END do { FENCE; __builtin_amdgcn_s_barrier(); FENCE; } while (0)

// ---------- K1: merged prep (x cast | W1 transpose | A transpose | B transpose) ----------
__global__ __launch_bounds__(256) void k_prep(const float* __restrict__ x,
                                              const float* __restrict__ W1,
                                              const float* __restrict__ A,
                                              const float* __restrict__ B,
                                              __hip_bfloat16* __restrict__ xb,
                                              __hip_bfloat16* __restrict__ w1t,
                                              __hip_bfloat16* __restrict__ at,
                                              __hip_bfloat16* __restrict__ bt) {
  __shared__ float s[64][65];
  const int bid = blockIdx.x;
  if (bid < 8192) {
    // x f32 -> bf16, 8 elems/thread
    size_t i = ((size_t)bid * 256 + threadIdx.x) * 8;
    float4 a = *(const float4*)(x + i);
    float4 b = *(const float4*)(x + i + 4);
    union { __hip_bfloat16 h[8]; int4 v; } u;
    u.h[0] = __float2bfloat16(a.x); u.h[1] = __float2bfloat16(a.y);
    u.h[2] = __float2bfloat16(a.z); u.h[3] = __float2bfloat16(a.w);
    u.h[4] = __float2bfloat16(b.x); u.h[5] = __float2bfloat16(b.y);
    u.h[6] = __float2bfloat16(b.z); u.h[7] = __float2bfloat16(b.w);
    *(int4*)(xb + i) = u.v;
  } else if (bid < 9216) {
    // W1 [k][n] -> W1T [n][k] bf16, 64x64 LDS tile
    int b = bid - 8192;
    int n0 = (b & 31) * 64, k0 = (b >> 5) * 64;
    for (int i = 0; i < 16; ++i) {
      int idx = threadIdx.x + i * 256;
      int r = idx >> 6, c = idx & 63;
      s[r][c] = W1[(size_t)(k0 + r) * HDIM + n0 + c];
    }
    __syncthreads();
    for (int i = 0; i < 16; ++i) {
      int idx = threadIdx.x + i * 256;
      int r = idx >> 6, c = idx & 63;
      w1t[(size_t)(n0 + r) * HDIM + k0 + c] = __float2bfloat16(s[c][r]);
    }
  } else if (bid < 9280) {
    // A [E][H][R] -> AT [E*R][H] bf16
    int b = bid - 9216;
    int e = b >> 3, ht = b & 7;
    float* sf = &s[0][0];
    const float* src = A + (size_t)e * (HDIM * RANK) + (size_t)ht * 256 * RANK;
    for (int i = 0; i < 8; ++i) sf[threadIdx.x + i * 256] = src[threadIdx.x + i * 256];
    __syncthreads();
    for (int i = 0; i < 8; ++i) {
      int idx = threadIdx.x + i * 256;
      int r = idx >> 8, hh = idx & 255;
      at[(size_t)(e * RANK + r) * HDIM + ht * 256 + hh] = __float2bfloat16(sf[hh * 8 + r]);
    }
  } else {
    // B [er 64][h 2048] -> Bt [h][er] bf16, 64x64 tile (32 blocks)
    int b = bid - 9280;
    int n0 = b * 64;                       // h base
    for (int i = 0; i < 16; ++i) {
      int idx = threadIdx.x + i * 256;
      int r = idx >> 6, c = idx & 63;      // r = er, c = h offset
      s[r][c] = B[(size_t)r * HDIM + n0 + c];
    }
    __syncthreads();
    for (int i = 0; i < 16; ++i) {
      int idx = threadIdx.x + i * 256;
      int r = idx >> 6, c = idx & 63;      // r = h offset, c = er
      bt[(size_t)(n0 + r) * 64 + c] = __float2bfloat16(s[c][r]);
    }
  }
}

// ---------- K3: h = relu(x @ W1 + b1) + router logit partials + t = x @ A ----------
// R7 structure (proven 76us / 38% MfmaUtil): 256x256, 8 waves (2Mx4N), BK=64,
// 144KB LDS, 3-bit row-XOR swizzle (bank-conflict-free), bijective XCD swizzle,
// 4 phases x {reads | stage | barrier | setprio MFMA | barrier}, one vmcnt(4)/tile.
// R10: sched_barrier(0) pins removed (see macro comment) — only delta vs R9.
__global__ __launch_bounds__(512, 2) void k_gemm_h8(const __hip_bfloat16* __restrict__ X,
                                                    const __hip_bfloat16* __restrict__ WT,
                                                    const float* __restrict__ b1,
                                                    const float* __restrict__ W2,
                                                    const __hip_bfloat16* __restrict__ AT,
                                                    float* __restrict__ plog,
                                                    float* __restrict__ tmat) {
  extern __shared__ char lds[];
  char* ldsA = lds;                 // [2 buf][2 half][128 rows][64 k] bf16 = 64KB
  char* ldsB = lds + 65536;         // same
  char* ldsT = lds + 131072;        // [2 buf][64 rows][64 k] bf16 = 16KB
  const int tid = threadIdx.x;
  const int wid = tid >> 6, lane = tid & 63;
  const int wr = wid >> 2, wc = wid & 3;        // 2 x 4 wave grid
  const int g = lane >> 4, c16 = lane & 15;
  const int xm = (c16 & 7) << 4;                // read-side swizzle XOR (3 row bits -> chunk)
  const int lin = blockIdx.y * 8 + blockIdx.x;  // gridDim.x == 8
  const int nid = (lin & 7) * 32 + (lin >> 3);  // bijective XCD remap (256 % 8 == 0)
  const int cb = nid & 7, rb = nid >> 3;
  const int m0 = rb * 256, n0 = cb * 256;
  const int NT = HDIM / 64;                     // 32 K-tiles

  int srow[2], scol[2];
#pragma unroll
  for (int q = 0; q < 2; ++q) {
    int L = (q * 512 + tid) * 16;               // linear phys byte within 16KB half
    int row = L >> 7;
    int chunkp = (L >> 4) & 7;
    srow[q] = row;
    scol[q] = (chunkp ^ (row & 7)) << 3;        // bf16 elements (chunk*8)
  }
  auto stage = [&](const __hip_bfloat16* gb, int rowBase, int kBase, char* half) {
    gload_lds16(gb + (size_t)(rowBase + srow[0]) * HDIM + kBase + scol[0], half + tid * 16);
    gload_lds16(gb + (size_t)(rowBase + srow[1]) * HDIM + kBase + scol[1], half + 8192 + tid * 16);
  };
  auto stageT = [&](int kBase, char* dstT) {
    int row = tid >> 3;
    int col = (((tid & 7) ^ (row & 7)) << 3);
    gload_lds16(AT + (size_t)row * HDIM + kBase + col, dstT + tid * 16);
  };
  auto ldA = [&](int b, int fr, int ks) -> bf16x8 {
    int byte = (((fr << 4) + c16) << 7) + (ks << 6) + (g << 4);
    return *(const bf16x8*)(ldsA + b * 32768 + wr * 16384 + (byte ^ xm));
  };
  auto ldB = [&](int b, int fc, int ks) -> bf16x8 {
    int byte = (((((wc & 1) << 6) + (fc << 4) + c16)) << 7) + (ks << 6) + (g << 4);
    return *(const bf16x8*)(ldsB + b * 32768 + (wc >> 1) * 16384 + (byte ^ xm));
  };
  auto ldAt = [&](int b, int ks) -> bf16x8 {
    int arow = cb * 32 + wr * 16 + c16;
    int byte = ((arow & 127) << 7) + (ks << 6) + (g << 4);
    return *(const bf16x8*)(ldsA + b * 32768 + (arow >> 7) * 16384 + (byte ^ xm));
  };
  auto ldT = [&](int tb, int ks) -> bf16x8 {
    int byte = (((wc << 4) + c16) << 7) + (ks << 6) + (g << 4);
    return *(const bf16x8*)(ldsT + tb * 8192 + (byte ^ xm));
  };

  f32x4 acc[8][4] = {};
  f32x4 acc_t = {};

  // ---- prologue: A(0) 4, B(0) 4, T(0) 1, B(1) 4 = 13 issues; vmcnt(5) covers A0/B0 ----
  stage(X,  m0,       0,  ldsA);
  stage(X,  m0 + 128, 0,  ldsA + 16384);
  stage(WT, n0,       0,  ldsB);
  stage(WT, n0 + 128, 0,  ldsB + 16384);
  stageT(0, ldsT);
  stage(WT, n0,       64, ldsB + 32768);
  stage(WT, n0 + 128, 64, ldsB + 32768 + 16384);
  FENCE; asm volatile("s_waitcnt vmcnt(5)" ::: "memory");
  __builtin_amdgcn_s_barrier();
  FENCE;

  for (int t = 0; t < NT; ++t) {
    const int b = t & 1;
    const int bn = b ^ 1;
    const int u1 = (t + 1 < NT) ? t + 1 : NT - 1; // clamped -> uniform vmcnt counts
    const int u2 = (t + 2 < NT) ? t + 2 : NT - 1;
    bf16x8 af[4][2], b01[2][2], b23[2][2];

    // ---------- P1: read A fr0-3 + B fc0-1 | stage A-lo(t+1) | vmcnt(4) | MFMA ----------
#pragma unroll
    for (int fr = 0; fr < 4; ++fr)
#pragma unroll
      for (int ks = 0; ks < 2; ++ks) af[fr][ks] = ldA(b, fr, ks);
#pragma unroll
    for (int fc = 0; fc < 2; ++fc)
#pragma unroll
      for (int ks = 0; ks < 2; ++ks) b01[fc][ks] = ldB(b, fc, ks);
    stage(X, m0, u1 * 64, ldsA + bn * 32768);
    SYNC_P1;
    __builtin_amdgcn_s_setprio(1);
#pragma unroll
    for (int fr = 0; fr < 4; ++fr)
#pragma unroll
      for (int fc = 0; fc < 2; ++fc)
#pragma unroll
        for (int ks = 0; ks < 2; ++ks)
          acc[fr][fc] = __builtin_amdgcn_mfma_f32_16x16x32_bf16(af[fr][ks], b01[fc][ks], acc[fr][fc], 0, 0, 0);
    __builtin_amdgcn_s_setprio(0);
    SYNC_END;

    // ---------- P2: read B fc2-3 | stage A-hi(t+1) | MFMA ----------
#pragma unroll
    for (int fc = 0; fc < 2; ++fc)
#pragma unroll
      for (int ks = 0; ks < 2; ++ks) b23[fc][ks] = ldB(b, fc + 2, ks);
    stage(X, m0 + 128, u1 * 64, ldsA + bn * 32768 + 16384);
    SYNC_MIDB;
    __builtin_amdgcn_s_setprio(1);
#pragma unroll
    for (int fr = 0; fr < 4; ++fr)
#pragma unroll
      for (int fc = 0; fc < 2; ++fc)
#pragma unroll
        for (int ks = 0; ks < 2; ++ks)
          acc[fr][fc + 2] = __builtin_amdgcn_mfma_f32_16x16x32_bf16(af[fr][ks], b23[fc][ks], acc[fr][fc + 2], 0, 0, 0);
    __builtin_amdgcn_s_setprio(0);
    SYNC_END;

    // ---------- P3: read A fr4-7 | stage B-lo(t+2), T(t+1) | MFMA ----------
#pragma unroll
    for (int fr = 0; fr < 4; ++fr)
#pragma unroll
      for (int ks = 0; ks < 2; ++ks) af[fr][ks] = ldA(b, fr + 4, ks);
    stage(WT, n0, u2 * 64, ldsB + b * 32768);
    stageT(u1 * 64, ldsT + bn * 8192);
    SYNC_MIDB;
    __builtin_amdgcn_s_setprio(1);
#pragma unroll
    for (int fr = 0; fr < 4; ++fr)
#pragma unroll
      for (int fc = 0; fc < 2; ++fc)
#pragma unroll
        for (int ks = 0; ks < 2; ++ks)
          acc[fr + 4][fc + 2] = __builtin_amdgcn_mfma_f32_16x16x32_bf16(af[fr][ks], b23[fc][ks], acc[fr + 4][fc + 2], 0, 0, 0);
    __builtin_amdgcn_s_setprio(0);
    SYNC_END;

    // ---------- P4: read t-frags | stage B-hi(t+2) | MFMA + 2 t-MFMA ----------
    bf16x8 ta0 = ldAt(b, 0), ta1 = ldAt(b, 1);
    bf16x8 tb0 = ldT(b, 0),  tb1 = ldT(b, 1);
    stage(WT, n0 + 128, u2 * 64, ldsB + b * 32768 + 16384);
    SYNC_MIDB;
    __builtin_amdgcn_s_setprio(1);
#pragma unroll
    for (int fr = 0; fr < 4; ++fr)
#pragma unroll
      for (int fc = 0; fc < 2; ++fc)
#pragma unroll
        for (int ks = 0; ks < 2; ++ks)
          acc[fr + 4][fc] = __builtin_amdgcn_mfma_f32_16x16x32_bf16(af[fr][ks], b01[fc][ks], acc[fr + 4][fc], 0, 0, 0);
    acc_t = __builtin_amdgcn_mfma_f32_16x16x32_bf16(ta0, tb0, acc_t, 0, 0, 0);
    acc_t = __builtin_amdgcn_mfma_f32_16x16x32_bf16(ta1, tb1, acc_t, 0, 0, 0);
    __builtin_amdgcn_s_setprio(0);
    SYNC_END;
  }

  // ---- t write: block's disjoint 32-row slice; D: col=c16 (er), row=g*4+q ----
  {
    int trow = m0 + cb * 32 + wr * 16 + g * 4;
    int er = wc * 16 + c16;
#pragma unroll
    for (int q = 0; q < 4; ++q)
      tmat[(size_t)(trow + q) * 64 + er] = acc_t[q];
  }

  // ---- fused epilogue: router logit partials via LDS transpose-reduce ----
  FENCE; asm volatile("s_waitcnt vmcnt(0)" ::: "memory");
  __builtin_amdgcn_s_barrier(); FENCE;
  float* red = (float*)lds;                      // 74KB < 144KB

  f32x4 w2lo[4], w2hi[4];
  float bias[4];
#pragma unroll
  for (int fc = 0; fc < 4; ++fc) {
    int col = n0 + wc * 64 + fc * 16 + c16;
    const float* wp = W2 + (size_t)col * EXP;
    w2lo[fc] = *(const f32x4*)wp;
    w2hi[fc] = *(const f32x4*)(wp + 4);
    bias[fc] = b1[col];
  }
  const int oidx = tid >> 1, prt = tid & 1;
  const int rrl = oidx >> 3, re = oidx & 7;      // reader's (rloc, e)
  for (int fr = 0; fr < 8; ++fr) {
#pragma unroll
    for (int r = 0; r < 4; ++r) {
      f32x4 p0 = {}, p1 = {};
#pragma unroll
      for (int fc = 0; fc < 4; ++fc) {
        float v = acc[fr][fc][r] + bias[fc];
        v = v > 0.f ? v : 0.f;                   // f32 h (no bf16 round-trip)
        p0 += v * w2lo[fc];
        p1 += v * w2hi[fc];
      }
      int base = (wc * 16 + c16) * 289 + (wr * 16 + g * 4 + r) * 9;
#pragma unroll
      for (int e = 0; e < 4; ++e) { red[base + e] = p0[e]; red[base + 4 + e] = p1[e]; }
    }
    __syncthreads();
    {
      float s = 0.f;
#pragma unroll
      for (int wq = 0; wq < 4; ++wq)
#pragma unroll
        for (int i = 0; i < 8; ++i)
          s += red[(wq * 16 + prt * 8 + i) * 289 + rrl * 9 + re];
      s += __shfl_xor(s, 1, 64);                 // combine prt halves
      if (prt == 0) {
        int grow = (rrl >> 4) * 128 + fr * 16 + (rrl & 15);
        plog[((size_t)cb * NROWS + m0 + grow) * 8 + re] = s;
      }
    }
    __syncthreads();
  }
}

// ---------- K6: fused softmax + MFMA out = (w .* t) @ B ----------
// 1024 blocks (256 row-groups x 4 col-slices), 256 thr (4 waves), 68KB dyn LDS.
__global__ __launch_bounds__(256) void k_final(const float* __restrict__ plog,
                                               const float* __restrict__ b2,
                                               const float* __restrict__ tmat,
                                               const __hip_bfloat16* __restrict__ Bt,
                                               float* __restrict__ out) {
  extern __shared__ char flds[];
  char* cl = flds;            // [32 rows][64 er] bf16, swizzled, 4KB
  char* bl = flds + 4096;     // [512 hcols][64 er] bf16, swizzled, 64KB
  const int t = threadIdx.x;
  const int wv = t >> 6, lane = t & 63;
  const int g = lane >> 4, c16 = lane & 15;
  const int xm = (c16 & 7) << 4;
  const int r0 = (blockIdx.x >> 2) * 32;
  const int c0 = (blockIdx.x & 3) * 512;

  // stage Bt slice: 16 rounds x 256 thr x 16B (linear dest, inverse-swizzled src)
  for (int i = 0; i < 16; ++i) {
    int L = (i * 256 + t) * 16;
    int row = L >> 7;
    int chunkp = (L >> 4) & 7;
    int scol = (chunkp ^ (row & 7)) << 3;
    gload_lds16(Bt + (size_t)(c0 + row) * 64 + scol, bl + L);
  }
  // softmax + weighted c (bf16) into cl
  {
    int row = t >> 3, e = t & 7;
    float lg = b2[e];
#pragma unroll
    for (int cbk = 0; cbk < 8; ++cbk)
      lg += plog[((size_t)cbk * NROWS + r0 + row) * 8 + e];
    float m = lg;
#pragma unroll
    for (int off = 4; off; off >>= 1) m = fmaxf(m, __shfl_xor(m, off, 64));
    float ex = __expf(lg - m);
    float s = ex;
#pragma unroll
    for (int off = 4; off; off >>= 1) s += __shfl_xor(s, off, 64);
    float w = ex / s;
    const float* src = tmat + (size_t)(r0 + row) * 64 + e * 8;
    f32x4 v0 = *(const f32x4*)src * w;
    f32x4 v1 = *(const f32x4*)(src + 4) * w;
    union { __hip_bfloat16 h[8]; int4 q; } u;
#pragma unroll
    for (int j = 0; j < 4; ++j) { u.h[j] = __float2bfloat16(v0[j]); u.h[4 + j] = __float2bfloat16(v1[j]); }
    int byte = (row << 7) + (e << 4);
    *(int4*)(cl + (byte ^ ((row & 7) << 4))) = u.q;
  }
  asm volatile("s_waitcnt vmcnt(0)" ::: "memory");
  __syncthreads();

  auto ldc = [&](int mi, int ks) -> bf16x8 {
    int byte = (((mi << 4) + c16) << 7) + (ks << 6) + (g << 4);
    return *(const bf16x8*)(cl + (byte ^ xm));
  };
  auto ldb = [&](int nj, int ks) -> bf16x8 {
    int rowb = (wv << 7) + (nj << 4) + c16;
    int byte = (rowb << 7) + (ks << 6) + (g << 4);
    return *(const bf16x8*)(bl + (byte ^ xm));
  };
  bf16x8 cA[2][2];
#pragma unroll
  for (int mi = 0; mi < 2; ++mi)
#pragma unroll
    for (int ks = 0; ks < 2; ++ks) cA[mi][ks] = ldc(mi, ks);
  f32x4 acc[2][8] = {};
#pragma unroll
  for (int nj = 0; nj < 8; ++nj) {
    bf16x8 b0 = ldb(nj, 0), b1v = ldb(nj, 1);
#pragma unroll
    for (int mi = 0; mi < 2; ++mi) {
      acc[mi][nj] = __builtin_amdgcn_mfma_f32_16x16x32_bf16(cA[mi][0], b0,  acc[mi][nj], 0, 0, 0);
      acc[mi][nj] = __builtin_amdgcn_mfma_f32_16x16x32_bf16(cA[mi][1], b1v, acc[mi][nj], 0, 0, 0);
    }
  }
  // D: col=c16 (h within nj tile), row=4g+q (n rows)
#pragma unroll
  for (int mi = 0; mi < 2; ++mi)
#pragma unroll
    for (int nj = 0; nj < 8; ++nj)
#pragma unroll
      for (int q = 0; q < 4; ++q)
        out[(size_t)(r0 + mi * 16 + g * 4 + q) * HDIM + c0 + wv * 128 + nj * 16 + c16] = acc[mi][nj][q];
}

extern "C" void kernel_launch(void* const* d_in, const int* in_sizes, int n_in,
                              void* d_out, int out_size, void* d_ws, size_t ws_size,
                              hipStream_t stream) {
  const float* x  = (const float*)d_in[0];
  const float* W1 = (const float*)d_in[1];
  const float* b1 = (const float*)d_in[2];
  const float* W2 = (const float*)d_in[3];
  const float* b2 = (const float*)d_in[4];
  const float* A  = (const float*)d_in[5];
  const float* B  = (const float*)d_in[6];
  float* out = (float*)d_out;

  char* ws = (char*)d_ws;
  // ws layout (bytes):
  //   xb   [8192*2048] bf16 : 33,554,432
  //   w1t  [2048*2048] bf16 :  8,388,608
  //   plog [8*8192*8]  f32  :  2,097,152
  //   at   [64*2048]   bf16 :    262,144
  //   bt   [2048*64]   bf16 :    262,144
  //   tmat [8192*64]   f32  :  2,097,152
  __hip_bfloat16* xb  = (__hip_bfloat16*)(ws);
  __hip_bfloat16* w1t = (__hip_bfloat16*)(ws + 33554432);
  float* plog         = (float*)(ws + 41943040);
  __hip_bfloat16* at  = (__hip_bfloat16*)(ws + 75497472);
  __hip_bfloat16* bt  = (__hip_bfloat16*)(ws + 75759616);
  float* tmat         = (float*)(ws + 76021760);
  if (ws_size < 84410368) return;  // insufficient scratch -> fail loudly

  hipFuncSetAttribute((const void*)k_gemm_h8,
                      hipFuncAttributeMaxDynamicSharedMemorySize, 147456);
  hipFuncSetAttribute((const void*)k_final,
                      hipFuncAttributeMaxDynamicSharedMemorySize, 69632);

  k_prep<<<8192 + 1024 + 64 + 32, 256, 0, stream>>>(x, W1, A, B, xb, w1t, at, bt);
  k_gemm_h8<<<dim3(HDIM / 256, NROWS / 256), 512, 147456, stream>>>(xb, w1t, b1, W2, at, plog, tmat);
  k_final<<<1024, 256, 69632, stream>>>(plog, b2, tmat, bt, out);
}

// Round 13
// 111.200 us; speedup vs baseline: 1.5557x; 1.0047x over previous
//
#include <hip/hip_runtime.h>
#include <hip/hip_bf16.h>

// Problem constants (fixed by reference)
#define NROWS 8192
#define HDIM  2048
#define EXP   8
#define RANK  8

typedef float  f32x4  __attribute__((ext_vector_type(4)));
typedef __bf16 bf16x8 __attribute__((ext_vector_type(8)));

// async global->LDS, 16B per lane; LDS dest must be wave-uniform (HW: base + lane*16)
__device__ __forceinline__ void gload_lds16(const void* g, void* l) {
  __builtin_amdgcn_global_load_lds((const __attribute__((address_space(1))) void*)g,
                                   (__attribute__((address_space(3))) void*)l, 16, 0, 0);
}

#define FENCE asm volatile("" ::: "memory")
// FROZEN LESSONS:
//  R8: collapsing 4-phase/8-barrier to 2 barriers regressed 76->111us (m196).
//  R10: sched_barrier(0) pins are neutral -> removed.
//  R11: 4-wave/128^2 remap of the t-fusion FAILED correctness (absmax 0.168,
//       un-diagnosed) -> this file is the verified 8-wave/256^2 R10 structure.
#define SYNC_P1 do { FENCE; asm volatile("s_waitcnt vmcnt(4)" ::: "memory"); \
  __builtin_amdgcn_s_barrier(); FENCE; } while (0)
#define SYNC_MIDB do { FENCE; __builtin_amdgcn_s_barrier(); FENCE; } while (0)
#define SYNC_END do { FENCE; __builtin_amdgcn_s_barrier(); FENCE; } while (0)

// ---------- K1: merged prep (x cast | W1 transpose | A transpose | B transpose) ----------
__global__ __launch_bounds__(256) void k_prep(const float* __restrict__ x,
                                              const float* __restrict__ W1,
                                              const float* __restrict__ A,
                                              const float* __restrict__ B,
                                              __hip_bfloat16* __restrict__ xb,
                                              __hip_bfloat16* __restrict__ w1t,
                                              __hip_bfloat16* __restrict__ at,
                                              __hip_bfloat16* __restrict__ bt) {
  __shared__ float s[64][65];
  const int bid = blockIdx.x;
  if (bid < 8192) {
    // x f32 -> bf16, 8 elems/thread
    size_t i = ((size_t)bid * 256 + threadIdx.x) * 8;
    float4 a = *(const float4*)(x + i);
    float4 b = *(const float4*)(x + i + 4);
    union { __hip_bfloat16 h[8]; int4 v; } u;
    u.h[0] = __float2bfloat16(a.x); u.h[1] = __float2bfloat16(a.y);
    u.h[2] = __float2bfloat16(a.z); u.h[3] = __float2bfloat16(a.w);
    u.h[4] = __float2bfloat16(b.x); u.h[5] = __float2bfloat16(b.y);
    u.h[6] = __float2bfloat16(b.z); u.h[7] = __float2bfloat16(b.w);
    *(int4*)(xb + i) = u.v;
  } else if (bid < 9216) {
    // W1 [k][n] -> W1T [n][k] bf16, 64x64 LDS tile
    int b = bid - 8192;
    int n0 = (b & 31) * 64, k0 = (b >> 5) * 64;
    for (int i = 0; i < 16; ++i) {
      int idx = threadIdx.x + i * 256;
      int r = idx >> 6, c = idx & 63;
      s[r][c] = W1[(size_t)(k0 + r) * HDIM + n0 + c];
    }
    __syncthreads();
    for (int i = 0; i < 16; ++i) {
      int idx = threadIdx.x + i * 256;
      int r = idx >> 6, c = idx & 63;
      w1t[(size_t)(n0 + r) * HDIM + k0 + c] = __float2bfloat16(s[c][r]);
    }
  } else if (bid < 9280) {
    // A [E][H][R] -> AT [E*R][H] bf16
    int b = bid - 9216;
    int e = b >> 3, ht = b & 7;
    float* sf = &s[0][0];
    const float* src = A + (size_t)e * (HDIM * RANK) + (size_t)ht * 256 * RANK;
    for (int i = 0; i < 8; ++i) sf[threadIdx.x + i * 256] = src[threadIdx.x + i * 256];
    __syncthreads();
    for (int i = 0; i < 8; ++i) {
      int idx = threadIdx.x + i * 256;
      int r = idx >> 8, hh = idx & 255;
      at[(size_t)(e * RANK + r) * HDIM + ht * 256 + hh] = __float2bfloat16(sf[hh * 8 + r]);
    }
  } else {
    // B [er 64][h 2048] -> Bt [h][er] bf16, 64x64 tile (32 blocks)
    int b = bid - 9280;
    int n0 = b * 64;                       // h base
    for (int i = 0; i < 16; ++i) {
      int idx = threadIdx.x + i * 256;
      int r = idx >> 6, c = idx & 63;      // r = er, c = h offset
      s[r][c] = B[(size_t)r * HDIM + n0 + c];
    }
    __syncthreads();
    for (int i = 0; i < 16; ++i) {
      int idx = threadIdx.x + i * 256;
      int r = idx >> 6, c = idx & 63;      // r = h offset, c = er
      bt[(size_t)(n0 + r) * 64 + c] = __float2bfloat16(s[c][r]);
    }
  }
}

// ---------- K3: h = relu(x @ W1 + b1) + router logit partials + t = x @ A ----------
// R7/R10 structure (verified 76us / 38% MfmaUtil): 256x256, 8 waves (2Mx4N), BK=64,
// 144KB LDS, 3-bit row-XOR swizzle (bank-conflict-free), bijective XCD swizzle,
// 4 phases x {reads | stage | barrier | setprio MFMA | barrier}, one vmcnt(4)/tile.
__global__ __launch_bounds__(512, 2) void k_gemm_h8(const __hip_bfloat16* __restrict__ X,
                                                    const __hip_bfloat16* __restrict__ WT,
                                                    const float* __restrict__ b1,
                                                    const float* __restrict__ W2,
                                                    const __hip_bfloat16* __restrict__ AT,
                                                    float* __restrict__ plog,
                                                    float* __restrict__ tmat) {
  extern __shared__ char lds[];
  char* ldsA = lds;                 // [2 buf][2 half][128 rows][64 k] bf16 = 64KB
  char* ldsB = lds + 65536;         // same
  char* ldsT = lds + 131072;        // [2 buf][64 rows][64 k] bf16 = 16KB
  const int tid = threadIdx.x;
  const int wid = tid >> 6, lane = tid & 63;
  const int wr = wid >> 2, wc = wid & 3;        // 2 x 4 wave grid
  const int g = lane >> 4, c16 = lane & 15;
  const int xm = (c16 & 7) << 4;                // read-side swizzle XOR (3 row bits -> chunk)
  const int lin = blockIdx.y * 8 + blockIdx.x;  // gridDim.x == 8
  const int nid = (lin & 7) * 32 + (lin >> 3);  // bijective XCD remap (256 % 8 == 0)
  const int cb = nid & 7, rb = nid >> 3;
  const int m0 = rb * 256, n0 = cb * 256;
  const int NT = HDIM / 64;                     // 32 K-tiles

  int srow[2], scol[2];
#pragma unroll
  for (int q = 0; q < 2; ++q) {
    int L = (q * 512 + tid) * 16;               // linear phys byte within 16KB half
    int row = L >> 7;
    int chunkp = (L >> 4) & 7;
    srow[q] = row;
    scol[q] = (chunkp ^ (row & 7)) << 3;        // bf16 elements (chunk*8)
  }
  auto stage = [&](const __hip_bfloat16* gb, int rowBase, int kBase, char* half) {
    gload_lds16(gb + (size_t)(rowBase + srow[0]) * HDIM + kBase + scol[0], half + tid * 16);
    gload_lds16(gb + (size_t)(rowBase + srow[1]) * HDIM + kBase + scol[1], half + 8192 + tid * 16);
  };
  auto stageT = [&](int kBase, char* dstT) {
    int row = tid >> 3;
    int col = (((tid & 7) ^ (row & 7)) << 3);
    gload_lds16(AT + (size_t)row * HDIM + kBase + col, dstT + tid * 16);
  };
  auto ldA = [&](int b, int fr, int ks) -> bf16x8 {
    int byte = (((fr << 4) + c16) << 7) + (ks << 6) + (g << 4);
    return *(const bf16x8*)(ldsA + b * 32768 + wr * 16384 + (byte ^ xm));
  };
  auto ldB = [&](int b, int fc, int ks) -> bf16x8 {
    int byte = (((((wc & 1) << 6) + (fc << 4) + c16)) << 7) + (ks << 6) + (g << 4);
    return *(const bf16x8*)(ldsB + b * 32768 + (wc >> 1) * 16384 + (byte ^ xm));
  };
  auto ldAt = [&](int b, int ks) -> bf16x8 {
    int arow = cb * 32 + wr * 16 + c16;
    int byte = ((arow & 127) << 7) + (ks << 6) + (g << 4);
    return *(const bf16x8*)(ldsA + b * 32768 + (arow >> 7) * 16384 + (byte ^ xm));
  };
  auto ldT = [&](int tb, int ks) -> bf16x8 {
    int byte = (((wc << 4) + c16) << 7) + (ks << 6) + (g << 4);
    return *(const bf16x8*)(ldsT + tb * 8192 + (byte ^ xm));
  };

  f32x4 acc[8][4] = {};
  f32x4 acc_t = {};

  // ---- prologue: A(0) 4, B(0) 4, T(0) 1, B(1) 4 = 13 issues; vmcnt(5) covers A0/B0 ----
  stage(X,  m0,       0,  ldsA);
  stage(X,  m0 + 128, 0,  ldsA + 16384);
  stage(WT, n0,       0,  ldsB);
  stage(WT, n0 + 128, 0,  ldsB + 16384);
  stageT(0, ldsT);
  stage(WT, n0,       64, ldsB + 32768);
  stage(WT, n0 + 128, 64, ldsB + 32768 + 16384);
  FENCE; asm volatile("s_waitcnt vmcnt(5)" ::: "memory");
  __builtin_amdgcn_s_barrier();
  FENCE;

  for (int t = 0; t < NT; ++t) {
    const int b = t & 1;
    const int bn = b ^ 1;
    const int u1 = (t + 1 < NT) ? t + 1 : NT - 1; // clamped -> uniform vmcnt counts
    const int u2 = (t + 2 < NT) ? t + 2 : NT - 1;
    bf16x8 af[4][2], b01[2][2], b23[2][2];

    // ---------- P1: read A fr0-3 + B fc0-1 | stage A-lo(t+1) | vmcnt(4) | MFMA ----------
#pragma unroll
    for (int fr = 0; fr < 4; ++fr)
#pragma unroll
      for (int ks = 0; ks < 2; ++ks) af[fr][ks] = ldA(b, fr, ks);
#pragma unroll
    for (int fc = 0; fc < 2; ++fc)
#pragma unroll
      for (int ks = 0; ks < 2; ++ks) b01[fc][ks] = ldB(b, fc, ks);
    stage(X, m0, u1 * 64, ldsA + bn * 32768);
    SYNC_P1;
    __builtin_amdgcn_s_setprio(1);
#pragma unroll
    for (int fr = 0; fr < 4; ++fr)
#pragma unroll
      for (int fc = 0; fc < 2; ++fc)
#pragma unroll
        for (int ks = 0; ks < 2; ++ks)
          acc[fr][fc] = __builtin_amdgcn_mfma_f32_16x16x32_bf16(af[fr][ks], b01[fc][ks], acc[fr][fc], 0, 0, 0);
    __builtin_amdgcn_s_setprio(0);
    SYNC_END;

    // ---------- P2: read B fc2-3 | stage A-hi(t+1) | MFMA ----------
#pragma unroll
    for (int fc = 0; fc < 2; ++fc)
#pragma unroll
      for (int ks = 0; ks < 2; ++ks) b23[fc][ks] = ldB(b, fc + 2, ks);
    stage(X, m0 + 128, u1 * 64, ldsA + bn * 32768 + 16384);
    SYNC_MIDB;
    __builtin_amdgcn_s_setprio(1);
#pragma unroll
    for (int fr = 0; fr < 4; ++fr)
#pragma unroll
      for (int fc = 0; fc < 2; ++fc)
#pragma unroll
        for (int ks = 0; ks < 2; ++ks)
          acc[fr][fc + 2] = __builtin_amdgcn_mfma_f32_16x16x32_bf16(af[fr][ks], b23[fc][ks], acc[fr][fc + 2], 0, 0, 0);
    __builtin_amdgcn_s_setprio(0);
    SYNC_END;

    // ---------- P3: read A fr4-7 | stage B-lo(t+2), T(t+1) | MFMA ----------
#pragma unroll
    for (int fr = 0; fr < 4; ++fr)
#pragma unroll
      for (int ks = 0; ks < 2; ++ks) af[fr][ks] = ldA(b, fr + 4, ks);
    stage(WT, n0, u2 * 64, ldsB + b * 32768);
    stageT(u1 * 64, ldsT + bn * 8192);
    SYNC_MIDB;
    __builtin_amdgcn_s_setprio(1);
#pragma unroll
    for (int fr = 0; fr < 4; ++fr)
#pragma unroll
      for (int fc = 0; fc < 2; ++fc)
#pragma unroll
        for (int ks = 0; ks < 2; ++ks)
          acc[fr + 4][fc + 2] = __builtin_amdgcn_mfma_f32_16x16x32_bf16(af[fr][ks], b23[fc][ks], acc[fr + 4][fc + 2], 0, 0, 0);
    __builtin_amdgcn_s_setprio(0);
    SYNC_END;

    // ---------- P4: read t-frags | stage B-hi(t+2) | MFMA + 2 t-MFMA ----------
    bf16x8 ta0 = ldAt(b, 0), ta1 = ldAt(b, 1);
    bf16x8 tb0 = ldT(b, 0),  tb1 = ldT(b, 1);
    stage(WT, n0 + 128, u2 * 64, ldsB + b * 32768 + 16384);
    SYNC_MIDB;
    __builtin_amdgcn_s_setprio(1);
#pragma unroll
    for (int fr = 0; fr < 4; ++fr)
#pragma unroll
      for (int fc = 0; fc < 2; ++fc)
#pragma unroll
        for (int ks = 0; ks < 2; ++ks)
          acc[fr + 4][fc] = __builtin_amdgcn_mfma_f32_16x16x32_bf16(af[fr][ks], b01[fc][ks], acc[fr + 4][fc], 0, 0, 0);
    acc_t = __builtin_amdgcn_mfma_f32_16x16x32_bf16(ta0, tb0, acc_t, 0, 0, 0);
    acc_t = __builtin_amdgcn_mfma_f32_16x16x32_bf16(ta1, tb1, acc_t, 0, 0, 0);
    __builtin_amdgcn_s_setprio(0);
    SYNC_END;
  }

  // ---- t write: block's disjoint 32-row slice; D: col=c16 (er), row=g*4+q ----
  {
    int trow = m0 + cb * 32 + wr * 16 + g * 4;
    int er = wc * 16 + c16;
#pragma unroll
    for (int q = 0; q < 4; ++q)
      tmat[(size_t)(trow + q) * 64 + er] = acc_t[q];
  }

  // ---- fused epilogue: router logit partials via LDS transpose-reduce ----
  FENCE; asm volatile("s_waitcnt vmcnt(0)" ::: "memory");
  __builtin_amdgcn_s_barrier(); FENCE;
  float* red = (float*)lds;                      // 74KB < 144KB

  f32x4 w2lo[4], w2hi[4];
  float bias[4];
#pragma unroll
  for (int fc = 0; fc < 4; ++fc) {
    int col = n0 + wc * 64 + fc * 16 + c16;
    const float* wp = W2 + (size_t)col * EXP;
    w2lo[fc] = *(const f32x4*)wp;
    w2hi[fc] = *(const f32x4*)(wp + 4);
    bias[fc] = b1[col];
  }
  const int oidx = tid >> 1, prt = tid & 1;
  const int rrl = oidx >> 3, re = oidx & 7;      // reader's (rloc, e)
  for (int fr = 0; fr < 8; ++fr) {
#pragma unroll
    for (int r = 0; r < 4; ++r) {
      f32x4 p0 = {}, p1 = {};
#pragma unroll
      for (int fc = 0; fc < 4; ++fc) {
        float v = acc[fr][fc][r] + bias[fc];
        v = v > 0.f ? v : 0.f;                   // f32 h (no bf16 round-trip)
        p0 += v * w2lo[fc];
        p1 += v * w2hi[fc];
      }
      int base = (wc * 16 + c16) * 289 + (wr * 16 + g * 4 + r) * 9;
#pragma unroll
      for (int e = 0; e < 4; ++e) { red[base + e] = p0[e]; red[base + 4 + e] = p1[e]; }
    }
    __syncthreads();
    {
      float s = 0.f;
#pragma unroll
      for (int wq = 0; wq < 4; ++wq)
#pragma unroll
        for (int i = 0; i < 8; ++i)
          s += red[(wq * 16 + prt * 8 + i) * 289 + rrl * 9 + re];
      s += __shfl_xor(s, 1, 64);                 // combine prt halves
      if (prt == 0) {
        int grow = (rrl >> 4) * 128 + fr * 16 + (rrl & 15);
        plog[((size_t)cb * NROWS + m0 + grow) * 8 + re] = s;
      }
    }
    __syncthreads();
  }
}

// ---------- K6: fused softmax + MFMA out = (w .* t) @ B ----------
// 1024 blocks (256 row-groups x 4 col-slices), 256 thr (4 waves), 68KB dyn LDS.
__global__ __launch_bounds__(256) void k_final(const float* __restrict__ plog,
                                               const float* __restrict__ b2,
                                               const float* __restrict__ tmat,
                                               const __hip_bfloat16* __restrict__ Bt,
                                               float* __restrict__ out) {
  extern __shared__ char flds[];
  char* cl = flds;            // [32 rows][64 er] bf16, swizzled, 4KB
  char* bl = flds + 4096;     // [512 hcols][64 er] bf16, swizzled, 64KB
  const int t = threadIdx.x;
  const int wv = t >> 6, lane = t & 63;
  const int g = lane >> 4, c16 = lane & 15;
  const int xm = (c16 & 7) << 4;
  const int r0 = (blockIdx.x >> 2) * 32;
  const int c0 = (blockIdx.x & 3) * 512;

  for (int i = 0; i < 16; ++i) {
    int L = (i * 256 + t) * 16;
    int row = L >> 7;
    int chunkp = (L >> 4) & 7;
    int scol = (chunkp ^ (row & 7)) << 3;
    gload_lds16(Bt + (size_t)(c0 + row) * 64 + scol, bl + L);
  }
  {
    int row = t >> 3, e = t & 7;
    float lg = b2[e];
#pragma unroll
    for (int cbk = 0; cbk < 8; ++cbk)
      lg += plog[((size_t)cbk * NROWS + r0 + row) * 8 + e];
    float m = lg;
#pragma unroll
    for (int off = 4; off; off >>= 1) m = fmaxf(m, __shfl_xor(m, off, 64));
    float ex = __expf(lg - m);
    float s = ex;
#pragma unroll
    for (int off = 4; off; off >>= 1) s += __shfl_xor(s, off, 64);
    float w = ex / s;
    const float* src = tmat + (size_t)(r0 + row) * 64 + e * 8;
    f32x4 v0 = *(const f32x4*)src * w;
    f32x4 v1 = *(const f32x4*)(src + 4) * w;
    union { __hip_bfloat16 h[8]; int4 q; } u;
#pragma unroll
    for (int j = 0; j < 4; ++j) { u.h[j] = __float2bfloat16(v0[j]); u.h[4 + j] = __float2bfloat16(v1[j]); }
    int byte = (row << 7) + (e << 4);
    *(int4*)(cl + (byte ^ ((row & 7) << 4))) = u.q;
  }
  asm volatile("s_waitcnt vmcnt(0)" ::: "memory");
  __syncthreads();

  auto ldc = [&](int mi, int ks) -> bf16x8 {
    int byte = (((mi << 4) + c16) << 7) + (ks << 6) + (g << 4);
    return *(const bf16x8*)(cl + (byte ^ xm));
  };
  auto ldb = [&](int nj, int ks) -> bf16x8 {
    int rowb = (wv << 7) + (nj << 4) + c16;
    int byte = (rowb << 7) + (ks << 6) + (g << 4);
    return *(const bf16x8*)(bl + (byte ^ xm));
  };
  bf16x8 cA[2][2];
#pragma unroll
  for (int mi = 0; mi < 2; ++mi)
#pragma unroll
    for (int ks = 0; ks < 2; ++ks) cA[mi][ks] = ldc(mi, ks);
  f32x4 acc[2][8] = {};
#pragma unroll
  for (int nj = 0; nj < 8; ++nj) {
    bf16x8 b0 = ldb(nj, 0), b1v = ldb(nj, 1);
#pragma unroll
    for (int mi = 0; mi < 2; ++mi) {
      acc[mi][nj] = __builtin_amdgcn_mfma_f32_16x16x32_bf16(cA[mi][0], b0,  acc[mi][nj], 0, 0, 0);
      acc[mi][nj] = __builtin_amdgcn_mfma_f32_16x16x32_bf16(cA[mi][1], b1v, acc[mi][nj], 0, 0, 0);
    }
  }
#pragma unroll
  for (int mi = 0; mi < 2; ++mi)
#pragma unroll
    for (int nj = 0; nj < 8; ++nj)
#pragma unroll
      for (int q = 0; q < 4; ++q)
        out[(size_t)(r0 + mi * 16 + g * 4 + q) * HDIM + c0 + wv * 128 + nj * 16 + c16] = acc[mi][nj][q];
}

extern "C" void kernel_launch(void* const* d_in, const int* in_sizes, int n_in,
                              void* d_out, int out_size, void* d_ws, size_t ws_size,
                              hipStream_t stream) {
  const float* x  = (const float*)d_in[0];
  const float* W1 = (const float*)d_in[1];
  const float* b1 = (const float*)d_in[2];
  const float* W2 = (const float*)d_in[3];
  const float* b2 = (const float*)d_in[4];
  const float* A  = (const float*)d_in[5];
  const float* B  = (const float*)d_in[6];
  float* out = (float*)d_out;

  char* ws = (char*)d_ws;
  // ws layout (bytes):
  //   xb   [8192*2048] bf16 : 33,554,432
  //   w1t  [2048*2048] bf16 :  8,388,608
  //   plog [8*8192*8]  f32  :  2,097,152
  //   at   [64*2048]   bf16 :    262,144
  //   bt   [2048*64]   bf16 :    262,144
  //   tmat [8192*64]   f32  :  2,097,152
  __hip_bfloat16* xb  = (__hip_bfloat16*)(ws);
  __hip_bfloat16* w1t = (__hip_bfloat16*)(ws + 33554432);
  float* plog         = (float*)(ws + 41943040);
  __hip_bfloat16* at  = (__hip_bfloat16*)(ws + 75497472);
  __hip_bfloat16* bt  = (__hip_bfloat16*)(ws + 75759616);
  float* tmat         = (float*)(ws + 76021760);
  if (ws_size < 84410368) return;  // insufficient scratch -> fail loudly

  hipFuncSetAttribute((const void*)k_gemm_h8,
                      hipFuncAttributeMaxDynamicSharedMemorySize, 147456);
  hipFuncSetAttribute((const void*)k_final,
                      hipFuncAttributeMaxDynamicSharedMemorySize, 69632);

  k_prep<<<8192 + 1024 + 64 + 32, 256, 0, stream>>>(x, W1, A, B, xb, w1t, at, bt);
  k_gemm_h8<<<dim3(HDIM / 256, NROWS / 256), 512, 147456, stream>>>(xb, w1t, b1, W2, at, plog, tmat);
  k_final<<<1024, 256, 69632, stream>>>(plog, b2, tmat, bt, out);
}